// Round 1
// baseline (142.316 us; speedup 1.0000x reference)
//
#include <hip/hip_runtime.h>

// TV loss via exact spatial-domain identity of the FFT pipeline:
//   gx[y,x] = in[y,x] - in[y,(x+1)%W]
//   gy[y,x] = in[y,x] - in[(y+1)%H,x]
//   result  = sum(sqrt(gx^2 + gy^2)) / (B*C*H*W)
// Shapes fixed: B=32, C=3, H=512, W=512 (fp32).
//
// One wave owns full 512-float rows (lane l holds floats 4l..4l+3 and
// 256+4l..256+4l+3, two coalesced 1-KB dwordx4 loads per row). Each wave
// walks an 8-row strip (was 4) with the same 3-row-pair rolling register
// double buffer: only 3 row-pairs (24 VGPRs payload) live at once ->
// __launch_bounds__(256,8) keeps VGPR<=64 for 8 waves/SIMD.
// 8-row strips load 9 rows per 8 produced -> boundary over-read drops
// from 25% to 12.5% (HBM traffic 120 MiB -> 108 MiB).
// All loads nontemporal (read-once streaming, evict-first).
// Right-neighbors via two __shfl((lane+1)&63) + lane-63 swap (handles the
// half-row seam at float 256 and the x-wrap 511->0).

#define DIM_H 512
#define DIM_W 512
#define PLANES 96                        // B*C
#define TOTAL (PLANES * DIM_H * DIM_W)   // 25165824
#define W4 128                           // float4 per row
#define STRIP 8                          // rows per wave
#define STRIPS_PER_PLANE (DIM_H / STRIP) // 64
#define NTHREADS 256
#define NBLOCKS (PLANES * STRIPS_PER_PLANE / 4)  // 1536 (4 waves/block)

// native clang vector type — __builtin_nontemporal_load requires this
typedef float vf4 __attribute__((ext_vector_type(4)));

struct F4 { float x, y, z, w; };

__device__ __forceinline__ F4 ldnt(const float* p) {
    vf4 v = __builtin_nontemporal_load((const vf4*)p);
    F4 r;
    r.x = v[0]; r.y = v[1]; r.z = v[2]; r.w = v[3];
    return r;
}

__global__ __launch_bounds__(NTHREADS, 8) void tv_partial(const float* __restrict__ in,
                                                          float* __restrict__ partial) {
    int wid  = blockIdx.x * (NTHREADS / 64) + (threadIdx.x >> 6);
    int lane = threadIdx.x & 63;
    int p = wid >> 6;                    // plane (64 strips/plane)
    int k = wid & (STRIPS_PER_PLANE - 1);

    int rb = (p << 16) + (k << 10) + lane;              // f4 idx of strip row 0
    int r8 = (k == STRIPS_PER_PLANE - 1) ? ((p << 16) + lane)  // y-wrap row
                                         : (rb + STRIP * W4);

    int src = (lane + 1) & 63;
    bool last = (lane == 63);
    float s = 0.0f;

#define TV_ROW(A, B, DA, DB)                                                   \
    do {                                                                       \
        float n0 = __shfl((A).x, src, 64);                                     \
        float n1 = __shfl((B).x, src, 64);                                     \
        float e0 = last ? n1 : n0; /* right of A.w */                          \
        float e1 = last ? n0 : n1; /* right of B.w (x-wrap) */                 \
        float t;                                                               \
        t = (A).x - (A).y; s += sqrtf(t*t + ((A).x-(DA).x)*((A).x-(DA).x));    \
        t = (A).y - (A).z; s += sqrtf(t*t + ((A).y-(DA).y)*((A).y-(DA).y));    \
        t = (A).z - (A).w; s += sqrtf(t*t + ((A).z-(DA).z)*((A).z-(DA).z));    \
        t = (A).w - e0;    s += sqrtf(t*t + ((A).w-(DA).w)*((A).w-(DA).w));    \
        t = (B).x - (B).y; s += sqrtf(t*t + ((B).x-(DB).x)*((B).x-(DB).x));    \
        t = (B).y - (B).z; s += sqrtf(t*t + ((B).y-(DB).y)*((B).y-(DB).y));    \
        t = (B).z - (B).w; s += sqrtf(t*t + ((B).z-(DB).z)*((B).z-(DB).z));    \
        t = (B).w - e1;    s += sqrtf(t*t + ((B).w-(DB).w)*((B).w-(DB).w));    \
    } while (0)

    // Rolling 3-buffer pipeline over 9 rows (rows 0..7 produced, row 8 =
    // down-neighbor boundary). Row r lives in buffer r%3; at TV_ROW(r,r+1)
    // the load of row r+2 has already been issued (2-row prefetch depth).
    F4 A0 = ldnt(in + 4 * (rb));               F4 B0 = ldnt(in + 4 * (rb + 64));
    F4 A1 = ldnt(in + 4 * (rb + 1 * W4));      F4 B1 = ldnt(in + 4 * (rb + 1 * W4 + 64));
    F4 A2 = ldnt(in + 4 * (rb + 2 * W4));      F4 B2 = ldnt(in + 4 * (rb + 2 * W4 + 64));

    TV_ROW(A0, B0, A1, B1);                                            // row 0 vs 1
    A0 = ldnt(in + 4 * (rb + 3 * W4));  B0 = ldnt(in + 4 * (rb + 3 * W4 + 64));
    TV_ROW(A1, B1, A2, B2);                                            // row 1 vs 2
    A1 = ldnt(in + 4 * (rb + 4 * W4));  B1 = ldnt(in + 4 * (rb + 4 * W4 + 64));
    TV_ROW(A2, B2, A0, B0);                                            // row 2 vs 3
    A2 = ldnt(in + 4 * (rb + 5 * W4));  B2 = ldnt(in + 4 * (rb + 5 * W4 + 64));
    TV_ROW(A0, B0, A1, B1);                                            // row 3 vs 4
    A0 = ldnt(in + 4 * (rb + 6 * W4));  B0 = ldnt(in + 4 * (rb + 6 * W4 + 64));
    TV_ROW(A1, B1, A2, B2);                                            // row 4 vs 5
    A1 = ldnt(in + 4 * (rb + 7 * W4));  B1 = ldnt(in + 4 * (rb + 7 * W4 + 64));
    TV_ROW(A2, B2, A0, B0);                                            // row 5 vs 6
    A2 = ldnt(in + 4 * (r8));           B2 = ldnt(in + 4 * (r8 + 64));
    TV_ROW(A0, B0, A1, B1);                                            // row 6 vs 7
    TV_ROW(A1, B1, A2, B2);                                            // row 7 vs 8 (wrap)
#undef TV_ROW

    // wave reduction
    #pragma unroll
    for (int off = 32; off > 0; off >>= 1)
        s += __shfl_down(s, off, 64);

    __shared__ float smem[NTHREADS / 64];
    int wave = threadIdx.x >> 6;
    if (lane == 0) smem[wave] = s;
    __syncthreads();
    if (threadIdx.x == 0)
        partial[blockIdx.x] = smem[0] + smem[1] + smem[2] + smem[3];
}

__global__ __launch_bounds__(256) void tv_final(const float* __restrict__ partial,
                                                float* __restrict__ out) {
    float s = 0.0f;
    for (int i = threadIdx.x; i < NBLOCKS; i += 256)
        s += partial[i];

    #pragma unroll
    for (int off = 32; off > 0; off >>= 1)
        s += __shfl_down(s, off, 64);

    __shared__ float smem[4];
    int lane = threadIdx.x & 63;
    int wave = threadIdx.x >> 6;
    if (lane == 0) smem[wave] = s;
    __syncthreads();
    if (threadIdx.x == 0)
        out[0] = (smem[0] + smem[1] + smem[2] + smem[3]) * (1.0f / (float)TOTAL);
}

extern "C" void kernel_launch(void* const* d_in, const int* in_sizes, int n_in,
                              void* d_out, int out_size, void* d_ws, size_t ws_size,
                              hipStream_t stream) {
    const float* in = (const float*)d_in[0];
    float* out = (float*)d_out;
    float* partial = (float*)d_ws;  // NBLOCKS floats of scratch

    tv_partial<<<NBLOCKS, NTHREADS, 0, stream>>>(in, partial);
    tv_final<<<1, 256, 0, stream>>>(partial, out);
}